// Round 5
// baseline (162.880 us; speedup 1.0000x reference)
//
#include <hip/hip_runtime.h>
#include <math.h>

#define TQ   32768
#define HWSZ 16384
#define CC   64
#define HH   128
#define WW   128
#define C3   192
#define C4   256
#define KS   7

typedef _Float16 half2v __attribute__((ext_vector_type(2)));
typedef _Float16 half4v __attribute__((ext_vector_type(4)));
typedef _Float16 half8v __attribute__((ext_vector_type(8)));
typedef float    f32x4  __attribute__((ext_vector_type(4)));

#define MFMA16(a, b, c) __builtin_amdgcn_mfma_f32_16x16x32_f16((a), (b), (c), 0, 0, 0)

// ============ K_A: LN1 + QKV GEMM fused. x NCHW -> qkv16 [T][192] ============
// grid 1024: bx>>1 = 64-token block, bx&1 = 96-j half. LN duplicated per j-half (cheap).
__global__ __launch_bounds__(256) void k_qkvln(const float* __restrict__ x,
        const float* __restrict__ lnw, const float* __restrict__ lnb,
        const float* __restrict__ qw, const float* __restrict__ qb,
        _Float16* __restrict__ qkv16) {
    __shared__ __align__(16) _Float16 A_s[64 * 72];
    __shared__ __align__(16) _Float16 B_s[96 * 72];
    __shared__ float ps1[256], ps2[256];
    __shared__ float m_s[64], r_s[64], w_s[64], b_s[64], bias_s[96];
    int tid = threadIdx.x;
    int t0 = (blockIdx.x >> 1) * 64;
    int j0 = (blockIdx.x & 1) * 96;
    if (tid < 64) { w_s[tid] = lnw[tid]; b_s[tid] = lnb[tid]; }
    if (tid < 96) bias_s[tid] = qb[j0 + tid];
    // stats pass: thread = (cq = wave, tok = lane); 16 channels each, coalesced across lanes
    int tok = tid & 63, cq = tid >> 6;
    int t = t0 + tok;
    int n = t >> 14, hw = t & (HWSZ - 1);
    const float* xr = x + ((size_t)n << 20) + hw;
    float v[16];
    float s = 0.f, s2 = 0.f;
#pragma unroll
    for (int e = 0; e < 16; ++e) {
        float f = xr[(cq * 16 + e) * HWSZ];
        v[e] = f; s += f; s2 += f * f;
    }
    ps1[tid] = s; ps2[tid] = s2;
    // stage B weights meanwhile
    for (int i = tid; i < 1536; i += 256) {
        int jj = i >> 4, seg = i & 15;
        float4 v4 = *(const float4*)&qw[(size_t)(j0 + jj) * 64 + seg * 4];
        half4v h4 = { (_Float16)v4.x, (_Float16)v4.y, (_Float16)v4.z, (_Float16)v4.w };
        *(half4v*)&B_s[jj * 72 + seg * 4] = h4;
    }
    __syncthreads();
    if (tid < 64) {
        float ss = ps1[tid] + ps1[64 + tid] + ps1[128 + tid] + ps1[192 + tid];
        float qq = ps2[tid] + ps2[64 + tid] + ps2[128 + tid] + ps2[192 + tid];
        float m = ss * (1.f / 64.f);
        float var = qq * (1.f / 64.f) - m * m;
        m_s[tid] = m; r_s[tid] = rsqrtf(var + 1e-5f);
    }
    __syncthreads();
    {
        float m = m_s[tok], r = r_s[tok];
        half8v o0, o1;
#pragma unroll
        for (int e = 0; e < 8; ++e) {
            int c = cq * 16 + e;
            o0[e] = (_Float16)((v[e] - m) * r * w_s[c] + b_s[c]);
        }
#pragma unroll
        for (int e = 0; e < 8; ++e) {
            int c = cq * 16 + 8 + e;
            o1[e] = (_Float16)((v[8 + e] - m) * r * w_s[c] + b_s[c]);
        }
        *(half8v*)&A_s[tok * 72 + cq * 16] = o0;
        *(half8v*)&A_s[tok * 72 + cq * 16 + 8] = o1;
    }
    __syncthreads();
    // GEMM: waves 2x2, wave tile 32t x 48j
    int lane = tid & 63, wv = tid >> 6;
    int quad = lane >> 4, l16 = lane & 15;
    int mt0 = (wv & 1) * 32, nt0 = (wv >> 1) * 48;
    f32x4 acc[2][3];
#pragma unroll
    for (int mf = 0; mf < 2; ++mf)
#pragma unroll
        for (int nf = 0; nf < 3; ++nf) acc[mf][nf] = (f32x4){0.f, 0.f, 0.f, 0.f};
#pragma unroll
    for (int ks = 0; ks < 64; ks += 32) {
        half8v a[2], bfr[3];
#pragma unroll
        for (int mf = 0; mf < 2; ++mf)
            a[mf] = *(const half8v*)&A_s[(mt0 + mf * 16 + l16) * 72 + ks + quad * 8];
#pragma unroll
        for (int nf = 0; nf < 3; ++nf)
            bfr[nf] = *(const half8v*)&B_s[(nt0 + nf * 16 + l16) * 72 + ks + quad * 8];
#pragma unroll
        for (int mf = 0; mf < 2; ++mf)
#pragma unroll
            for (int nf = 0; nf < 3; ++nf) acc[mf][nf] = MFMA16(a[mf], bfr[nf], acc[mf][nf]);
    }
    const float qscale = 0.17677669529663687f;
#pragma unroll
    for (int mf = 0; mf < 2; ++mf)
#pragma unroll
        for (int nf = 0; nf < 3; ++nf) {
            int j = j0 + nt0 + nf * 16 + l16;
            float bias = bias_s[nt0 + nf * 16 + l16];
            float sc = (j < 64) ? qscale : 1.f;
#pragma unroll
            for (int r = 0; r < 4; ++r) {
                int tt = t0 + mt0 + mf * 16 + quad * 4 + r;
                qkv16[(size_t)tt * C3 + j] = (_Float16)((acc[mf][nf][r] + bias) * sc);
            }
        }
}

// ============ K_B: neighborhood attention, one head per block ============
// grid 1024: (n, z, 16x16 tiles of 8x8 queries). LDS ~38KB -> 4 blocks/CU.
#define KST 34
__global__ __launch_bounds__(256) void k_attn(const _Float16* __restrict__ qkv16,
        const float* __restrict__ rpb, _Float16* __restrict__ attn16) {
    __shared__ __align__(16) _Float16 k_s[196 * KST];
    __shared__ __align__(16) _Float16 v_s[196 * KST];
    __shared__ __align__(16) _Float16 q_s[64 * KST];
    __shared__ _Float16 s_s[64 * 50];
    __shared__ float rpb_s[169];
    int tid = threadIdx.x;
    int bx = blockIdx.x;
    int n = bx >> 9, z = (bx >> 8) & 1;
    int th = (bx >> 4) & 15, tw = bx & 15;
    int h0 = th * 8, w0 = tw * 8;
    int wr0 = min(max(h0 - 3, 0), HH - 14);
    int ww0 = min(max(w0 - 3, 0), WW - 14);
    int tbase = n << 14;
    if (tid < 169) rpb_s[tid] = rpb[z * 169 + tid];
    // stage k/v (this head only): 196 tokens x 32 ch each
    for (int i = tid; i < 784; i += 256) {
        int tok = i >> 2, u = i & 3;
        int wi = (tok * 586) >> 13;          // tok / 14
        int wj = tok - wi * 14;
        const _Float16* src = qkv16 +
            (size_t)(tbase + (wr0 + wi) * WW + ww0 + wj) * C3 + 64 + z * 32 + u * 8;
        *(half8v*)&k_s[tok * KST + u * 8] = *(const half8v*)src;
        *(half8v*)&v_s[tok * KST + u * 8] = *(const half8v*)(src + 64);
    }
    {   // stage q: exactly 256 chunks
        int q = tid >> 2, u = tid & 3;
        int qg = tbase + (h0 + (q >> 3)) * WW + (w0 + (q & 7));
        *(half8v*)&q_s[q * KST + u * 8] = *(const half8v*)&qkv16[(size_t)qg * C3 + z * 32 + u * 8];
    }
    __syncthreads();
    // query geometry helpers
    int q = tid & 63;
    int qy = q >> 3, qx = q & 7;
    int h = h0 + qy, wc = w0 + qx;
    int sh = min(max(h - 3, 0), HH - KS);
    int sw = min(max(wc - 3, 0), WW - KS);
    int oh = sh - wr0, ow = sw - ww0;
    int dhp = h - sh + 6, dwp = wc - sw + 6;
    // ---- phase B: scores. wave = neighbor-quarter, lane = query ----
    {
        int nbq = tid >> 6;
        const half8v* qp = (const half8v*)&q_s[q * KST];
        half8v q0 = qp[0], q1 = qp[1], q2 = qp[2], q3 = qp[3];
        int i7 = 0, j7 = nbq;
        int cnt = (nbq == 0) ? 13 : 12;
        int nb = nbq;
        for (int it = 0; it < cnt; ++it) {
            int tok = (oh + i7) * 14 + (ow + j7);
            const half8v* kp = (const half8v*)&k_s[tok * KST];
            half2v a2 = { (_Float16)0.f, (_Float16)0.f };
            a2 += (half2v){kp[0].s0, kp[0].s1} * (half2v){q0.s0, q0.s1};
            a2 += (half2v){kp[0].s2, kp[0].s3} * (half2v){q0.s2, q0.s3};
            a2 += (half2v){kp[0].s4, kp[0].s5} * (half2v){q0.s4, q0.s5};
            a2 += (half2v){kp[0].s6, kp[0].s7} * (half2v){q0.s6, q0.s7};
            a2 += (half2v){kp[1].s0, kp[1].s1} * (half2v){q1.s0, q1.s1};
            a2 += (half2v){kp[1].s2, kp[1].s3} * (half2v){q1.s2, q1.s3};
            a2 += (half2v){kp[1].s4, kp[1].s5} * (half2v){q1.s4, q1.s5};
            a2 += (half2v){kp[1].s6, kp[1].s7} * (half2v){q1.s6, q1.s7};
            a2 += (half2v){kp[2].s0, kp[2].s1} * (half2v){q2.s0, q2.s1};
            a2 += (half2v){kp[2].s2, kp[2].s3} * (half2v){q2.s2, q2.s3};
            a2 += (half2v){kp[2].s4, kp[2].s5} * (half2v){q2.s4, q2.s5};
            a2 += (half2v){kp[2].s6, kp[2].s7} * (half2v){q2.s6, q2.s7};
            a2 += (half2v){kp[3].s0, kp[3].s1} * (half2v){q3.s0, q3.s1};
            a2 += (half2v){kp[3].s2, kp[3].s3} * (half2v){q3.s2, q3.s3};
            a2 += (half2v){kp[3].s4, kp[3].s5} * (half2v){q3.s4, q3.s5};
            a2 += (half2v){kp[3].s6, kp[3].s7} * (half2v){q3.s6, q3.s7};
            float sc = (float)a2.x + (float)a2.y + rpb_s[(dhp - i7) * 13 + (dwp - j7)];
            s_s[q * 50 + nb] = (_Float16)sc;
            nb += 4;
            j7 += 4; if (j7 >= 7) { j7 -= 7; ++i7; }
        }
    }
    __syncthreads();
    // ---- phase C: softmax, thread per query ----
    if (tid < 64) {
        _Float16* sp = &s_s[tid * 50];
        float mx = -1e30f;
        for (int i = 0; i < 49; ++i) mx = fmaxf(mx, (float)sp[i]);
        float sum = 0.f;
        for (int i = 0; i < 49; ++i) {
            float e = __expf((float)sp[i] - mx);
            sum += e;
            sp[i] = (_Float16)e;
        }
        float inv = 1.f / sum;
        for (int i = 0; i < 49; ++i) sp[i] = (_Float16)((float)sp[i] * inv);
    }
    __syncthreads();
    // ---- phase D: PV. wave = 8-channel group, lane = query ----
    {
        int c8 = tid >> 6;
        const _Float16* pp = &s_s[q * 50];
        half2v acc[4];
#pragma unroll
        for (int jv = 0; jv < 4; ++jv) acc[jv] = (half2v){ (_Float16)0.f, (_Float16)0.f };
        int i7 = 0, j7 = 0;
        for (int nb = 0; nb < 49; ++nb) {
            int tok = (oh + i7) * 14 + (ow + j7);
            _Float16 p = pp[nb];
            half2v p2 = { p, p };
            half8v vv = *(const half8v*)&v_s[tok * KST + c8 * 8];
            acc[0] += (half2v){vv.s0, vv.s1} * p2;
            acc[1] += (half2v){vv.s2, vv.s3} * p2;
            acc[2] += (half2v){vv.s4, vv.s5} * p2;
            acc[3] += (half2v){vv.s6, vv.s7} * p2;
            ++j7; if (j7 == 7) { j7 = 0; ++i7; }
        }
        int qg = tbase + h * WW + wc;
        half8v o = { acc[0].x, acc[0].y, acc[1].x, acc[1].y,
                     acc[2].x, acc[2].y, acc[3].x, acc[3].y };
        *(half8v*)&attn16[(size_t)qg * CC + z * 32 + c8 * 8] = o;
    }
}

// ============ K_C: proj GEMM + residual(x NCHW) + LN2 fused ============
// grid 512 (64-token blocks). Outputs x2_16 and xn2_16 (both [T][64] f16).
__global__ __launch_bounds__(256) void k_projln(const _Float16* __restrict__ ain,
        const float* __restrict__ pw, const float* __restrict__ pb,
        const float* __restrict__ x,
        const float* __restrict__ ln2w, const float* __restrict__ ln2b,
        _Float16* __restrict__ x2_16, _Float16* __restrict__ xn2_16) {
    __shared__ union {
        struct { __align__(16) _Float16 A[64 * 72]; __align__(16) _Float16 B[64 * 72]; } st;
        float x2t[64 * 67];
    } u;
    __shared__ float ps1[256], ps2[256];
    __shared__ float m_s[64], r_s[64], w_s[64], b_s[64], pbias[64];
    int tid = threadIdx.x;
    int t0 = blockIdx.x * 64;
    int n = t0 >> 14, hw0 = t0 & (HWSZ - 1);
    if (tid < 64) { w_s[tid] = ln2w[tid]; b_s[tid] = ln2b[tid]; pbias[tid] = pb[tid]; }
    for (int i = tid; i < 512; i += 256) {
        int tok = i >> 3, u8 = i & 7;
        *(half8v*)&u.st.A[tok * 72 + u8 * 8] = *(const half8v*)&ain[(size_t)(t0 + tok) * 64 + u8 * 8];
    }
    for (int i = tid; i < 1024; i += 256) {
        int jj = i >> 4, seg = i & 15;
        float4 v4 = *(const float4*)&pw[(size_t)jj * 64 + seg * 4];
        half4v h4 = { (_Float16)v4.x, (_Float16)v4.y, (_Float16)v4.z, (_Float16)v4.w };
        *(half4v*)&u.st.B[jj * 72 + seg * 4] = h4;
    }
    __syncthreads();
    int lane = tid & 63, wv = tid >> 6;
    int quad = lane >> 4, l16 = lane & 15;
    int mt0 = wv * 16;
    f32x4 acc[4];
#pragma unroll
    for (int nf = 0; nf < 4; ++nf) acc[nf] = (f32x4){0.f, 0.f, 0.f, 0.f};
#pragma unroll
    for (int ks = 0; ks < 64; ks += 32) {
        half8v a = *(const half8v*)&u.st.A[(mt0 + l16) * 72 + ks + quad * 8];
        half8v bfr[4];
#pragma unroll
        for (int nf = 0; nf < 4; ++nf)
            bfr[nf] = *(const half8v*)&u.st.B[(nf * 16 + l16) * 72 + ks + quad * 8];
#pragma unroll
        for (int nf = 0; nf < 4; ++nf) acc[nf] = MFMA16(a, bfr[nf], acc[nf]);
    }
    __syncthreads();
    // epilogue: + bias + residual (float4 from NCHW x) -> x2 tile in LDS (stride 67)
#pragma unroll
    for (int nf = 0; nf < 4; ++nf) {
        int j = nf * 16 + l16;
        float bias = pbias[j];
        int hwl = hw0 + mt0 + quad * 4;
        float4 rx = *(const float4*)&x[((size_t)(n * CC + j) << 14) + hwl];
#pragma unroll
        for (int r = 0; r < 4; ++r) {
            int tl = mt0 + quad * 4 + r;
            u.x2t[tl * 67 + j] = acc[nf][r] + bias + ((const float*)&rx)[r];
        }
    }
    __syncthreads();
    // LN2 stats: thread = (cq, tok)
    int tok = tid & 63, cq = tid >> 6;
    {
        float s = 0.f, s2 = 0.f;
#pragma unroll
        for (int e = 0; e < 16; ++e) {
            float f = u.x2t[tok * 67 + cq * 16 + e];
            s += f; s2 += f * f;
        }
        ps1[tid] = s; ps2[tid] = s2;
    }
    __syncthreads();
    if (tid < 64) {
        float ss = ps1[tid] + ps1[64 + tid] + ps1[128 + tid] + ps1[192 + tid];
        float qq = ps2[tid] + ps2[64 + tid] + ps2[128 + tid] + ps2[192 + tid];
        float m = ss * (1.f / 64.f);
        float var = qq * (1.f / 64.f) - m * m;
        m_s[tid] = m; r_s[tid] = rsqrtf(var + 1e-5f);
    }
    __syncthreads();
    {
        float m = m_s[tok], r = r_s[tok];
        half8v h0, h1, n0, n1;
#pragma unroll
        for (int e = 0; e < 8; ++e) {
            int c = cq * 16 + e;
            float f = u.x2t[tok * 67 + c];
            h0[e] = (_Float16)f;
            n0[e] = (_Float16)((f - m) * r * w_s[c] + b_s[c]);
        }
#pragma unroll
        for (int e = 0; e < 8; ++e) {
            int c = cq * 16 + 8 + e;
            float f = u.x2t[tok * 67 + c];
            h1[e] = (_Float16)f;
            n1[e] = (_Float16)((f - m) * r * w_s[c] + b_s[c]);
        }
        size_t base = (size_t)(t0 + tok) * 64 + cq * 16;
        *(half8v*)&x2_16[base] = h0;  *(half8v*)&x2_16[base + 8] = h1;
        *(half8v*)&xn2_16[base] = n0; *(half8v*)&xn2_16[base + 8] = n1;
    }
}

// ============ K_D: FC1 GEMM + exact GELU. xn2_16 -> hbuf16 [T][256] ============
// grid 1024: bx>>1 = 64-token block, bx&1 = 128-j half. Waves 2x2, tile 32t x 64j.
__global__ __launch_bounds__(256) void k_fc1(const _Float16* __restrict__ xin,
        const float* __restrict__ fw, const float* __restrict__ fb,
        _Float16* __restrict__ hbuf16) {
    __shared__ __align__(16) _Float16 A_s[64 * 72];
    __shared__ __align__(16) _Float16 B_s[128 * 72];
    __shared__ float bias_s[128];
    int tid = threadIdx.x;
    int t0 = (blockIdx.x >> 1) * 64;
    int j0 = (blockIdx.x & 1) * 128;
    for (int i = tid; i < 512; i += 256) {
        int tok = i >> 3, u8 = i & 7;
        *(half8v*)&A_s[tok * 72 + u8 * 8] = *(const half8v*)&xin[(size_t)(t0 + tok) * 64 + u8 * 8];
    }
    for (int i = tid; i < 2048; i += 256) {
        int jj = i >> 4, seg = i & 15;
        float4 v4 = *(const float4*)&fw[(size_t)(j0 + jj) * 64 + seg * 4];
        half4v h4 = { (_Float16)v4.x, (_Float16)v4.y, (_Float16)v4.z, (_Float16)v4.w };
        *(half4v*)&B_s[jj * 72 + seg * 4] = h4;
    }
    if (tid < 128) bias_s[tid] = fb[j0 + tid];
    __syncthreads();
    int lane = tid & 63, wv = tid >> 6;
    int quad = lane >> 4, l16 = lane & 15;
    int mt0 = (wv & 1) * 32, nt0 = (wv >> 1) * 64;
    f32x4 acc[2][4];
#pragma unroll
    for (int mf = 0; mf < 2; ++mf)
#pragma unroll
        for (int nf = 0; nf < 4; ++nf) acc[mf][nf] = (f32x4){0.f, 0.f, 0.f, 0.f};
#pragma unroll
    for (int ks = 0; ks < 64; ks += 32) {
        half8v a[2], bfr[4];
#pragma unroll
        for (int mf = 0; mf < 2; ++mf)
            a[mf] = *(const half8v*)&A_s[(mt0 + mf * 16 + l16) * 72 + ks + quad * 8];
#pragma unroll
        for (int nf = 0; nf < 4; ++nf)
            bfr[nf] = *(const half8v*)&B_s[(nt0 + nf * 16 + l16) * 72 + ks + quad * 8];
#pragma unroll
        for (int mf = 0; mf < 2; ++mf)
#pragma unroll
            for (int nf = 0; nf < 4; ++nf) acc[mf][nf] = MFMA16(a[mf], bfr[nf], acc[mf][nf]);
    }
#pragma unroll
    for (int mf = 0; mf < 2; ++mf)
#pragma unroll
        for (int nf = 0; nf < 4; ++nf) {
            int j = j0 + nt0 + nf * 16 + l16;
            float bias = bias_s[nt0 + nf * 16 + l16];
#pragma unroll
            for (int r = 0; r < 4; ++r) {
                int t = t0 + mt0 + mf * 16 + quad * 4 + r;
                float v = acc[mf][nf][r] + bias;
                float g = 0.5f * v * (1.f + erff(v * 0.70710678118654752f));
                hbuf16[(size_t)t * C4 + j] = (_Float16)g;
            }
        }
}

// ============ K_E: FC2 GEMM (K=256) + residual + NCHW f32 out ============
// grid 512 (64-token blocks). Waves tile 16t x 64j, 4 K-panels.
__global__ __launch_bounds__(256) void k_fc2(const _Float16* __restrict__ hbuf16,
        const float* __restrict__ fw, const float* __restrict__ fb,
        const _Float16* __restrict__ x2_16, float* __restrict__ out) {
    __shared__ union {
        struct { __align__(16) _Float16 A[64 * 72]; __align__(16) _Float16 B[64 * 72]; } st;
        float tr[64 * 67];
    } u;
    __shared__ float fb_s[64];
    int tid = threadIdx.x;
    int t0 = blockIdx.x * 64;
    int n = t0 >> 14, hw0 = t0 & (HWSZ - 1);
    int lane = tid & 63, wv = tid >> 6;
    int quad = lane >> 4, l16 = lane & 15;
    int mt0 = wv * 16;
    if (tid < 64) fb_s[tid] = fb[tid];
    f32x4 acc[4];
#pragma unroll
    for (int nf = 0; nf < 4; ++nf) acc[nf] = (f32x4){0.f, 0.f, 0.f, 0.f};
    for (int kp = 0; kp < 4; ++kp) {
        if (kp) __syncthreads();
        for (int i = tid; i < 512; i += 256) {
            int tok = i >> 3, u8 = i & 7;
            *(half8v*)&u.st.A[tok * 72 + u8 * 8] =
                *(const half8v*)&hbuf16[(size_t)(t0 + tok) * C4 + kp * 64 + u8 * 8];
        }
        for (int i = tid; i < 1024; i += 256) {
            int jj = i >> 4, seg = i & 15;
            float4 v4 = *(const float4*)&fw[(size_t)jj * C4 + kp * 64 + seg * 4];
            half4v h4 = { (_Float16)v4.x, (_Float16)v4.y, (_Float16)v4.z, (_Float16)v4.w };
            *(half4v*)&u.st.B[jj * 72 + seg * 4] = h4;
        }
        __syncthreads();
#pragma unroll
        for (int ks = 0; ks < 64; ks += 32) {
            half8v a = *(const half8v*)&u.st.A[(mt0 + l16) * 72 + ks + quad * 8];
            half8v bfr[4];
#pragma unroll
            for (int nf = 0; nf < 4; ++nf)
                bfr[nf] = *(const half8v*)&u.st.B[(nf * 16 + l16) * 72 + ks + quad * 8];
#pragma unroll
            for (int nf = 0; nf < 4; ++nf) acc[nf] = MFMA16(a, bfr[nf], acc[nf]);
        }
    }
    __syncthreads();
#pragma unroll
    for (int nf = 0; nf < 4; ++nf) {
        int j = nf * 16 + l16;
        float bias = fb_s[j];
#pragma unroll
        for (int r = 0; r < 4; ++r) {
            int tl = mt0 + quad * 4 + r;
            float v = acc[nf][r] + bias + (float)x2_16[(size_t)(t0 + tl) * 64 + j];
            u.tr[j * 67 + tl] = v;
        }
    }
    __syncthreads();
    for (int i = tid; i < 1024; i += 256) {
        int j = i >> 4, seg = i & 15;
        float4 v = *(const float4*)&u.tr[j * 67 + seg * 4];
        *(float4*)&out[((size_t)(n * CC + j) << 14) + hw0 + seg * 4] = v;
    }
}

extern "C" void kernel_launch(void* const* d_in, const int* in_sizes, int n_in,
                              void* d_out, int out_size, void* d_ws, size_t ws_size,
                              hipStream_t stream) {
    const float* x      = (const float*)d_in[0];
    const float* qkv_w  = (const float*)d_in[1];
    const float* qkv_b  = (const float*)d_in[2];
    const float* proj_w = (const float*)d_in[3];
    const float* proj_b = (const float*)d_in[4];
    const float* rpb    = (const float*)d_in[5];
    const float* ln1_w  = (const float*)d_in[6];
    const float* ln1_b  = (const float*)d_in[7];
    const float* ln2_w  = (const float*)d_in[8];
    const float* ln2_b  = (const float*)d_in[9];
    const float* fc1_w  = (const float*)d_in[10];
    const float* fc1_b  = (const float*)d_in[11];
    const float* fc2_w  = (const float*)d_in[12];
    const float* fc2_b  = (const float*)d_in[13];
    float* out = (float*)d_out;
    char* ws = (char*)d_ws;

    _Float16* qkv16  = (_Float16*)(ws);                 // 12.58 MB [T][192]
    _Float16* attn16 = (_Float16*)(ws + 12582912);      //  4.19 MB [T][64]
    _Float16* x2_16  = (_Float16*)(ws + 16777216);      //  4.19 MB [T][64]
    _Float16* xn2_16 = (_Float16*)(ws + 20971520);      //  4.19 MB [T][64]
    _Float16* hbuf16 = (_Float16*)(ws + 25165824);      // 16.78 MB [T][256]

    k_qkvln <<<1024, 256, 0, stream>>>(x, ln1_w, ln1_b, qkv_w, qkv_b, qkv16);
    k_attn  <<<1024, 256, 0, stream>>>(qkv16, rpb, attn16);
    k_projln<<<512,  256, 0, stream>>>(attn16, proj_w, proj_b, x, ln2_w, ln2_b, x2_16, xn2_16);
    k_fc1   <<<1024, 256, 0, stream>>>(xn2_16, fc1_w, fc1_b, hbuf16);
    k_fc2   <<<512,  256, 0, stream>>>(hbuf16, fc2_w, fc2_b, x2_16, out);
}